// Round 9
// baseline (1103.415 us; speedup 1.0000x reference)
//
#include <hip/hip_runtime.h>

#define LQ 2048
#define LK 2048
#define DD 1024
#define NB 8
#define NSL 8192   // elements per (dbuf,half) region: 128 slots x 64 cols
#define SSHIFT 125.0f   // row-uniform score shift: centers high-p scores near 0 for fp16 storage

typedef __attribute__((ext_vector_type(4))) float f4;
typedef __attribute__((ext_vector_type(4))) float f32x4;
typedef __attribute__((ext_vector_type(8))) short s16x8;
typedef __attribute__((ext_vector_type(8))) _Float16 h16x8;
typedef __attribute__((ext_vector_type(4))) _Float16 h16x4;
typedef __attribute__((ext_vector_type(2))) unsigned long long u64x2_t;

__device__ __forceinline__ void gload_lds16(const _Float16* g, const _Float16* l) {
  __builtin_amdgcn_global_load_lds((const __attribute__((address_space(1))) void*)g,
                                   (__attribute__((address_space(3))) void*)l, 16, 0, 0);
}

// ============ conv: pure streaming fp32 -> fp16 for Q and K ============

__global__ __launch_bounds__(256) void conv_flat(const float* __restrict__ Q,
                                                 const float* __restrict__ K,
                                                 _Float16* __restrict__ Qh,
                                                 _Float16* __restrict__ Kh) {
  const size_t nQ4 = (size_t)NB * LQ * DD / 4;
  const size_t tot = 2 * nQ4;
  const size_t stride = (size_t)gridDim.x * blockDim.x;
  for (size_t i = (size_t)blockIdx.x * blockDim.x + threadIdx.x; i < tot; i += stride) {
    const f4* src; _Float16* dst; size_t k;
    if (i < nQ4) { src = (const f4*)Q; dst = Qh; k = i; }
    else { src = (const f4*)K; dst = Kh; k = i - nQ4; }
    f4 v = src[k];
    h16x4 h;
#pragma unroll
    for (int j = 0; j < 4; ++j) h[j] = (_Float16)v[j];
    *(h16x4*)(dst + k * 4) = h;
  }
}

// ============ 256x256 4-phase GEMM core (verified; unchanged) ============
// 8 GEMM waves (2M x 4N), per-wave C = 128x64, BK=64 double-buffered halves,
// counted vmcnt, strictly-after staging ledger. Barrier count = 1 + 4*(NT/2).

__device__ __forceinline__ void load_af(const _Float16* ASm, int p, int mh,
                                        int wm, int lm, int grp, h16x8 af[4][2]) {
#pragma unroll
  for (int mti = 0; mti < 4; ++mti) {
    int slot = wm * 64 + mti * 16 + lm;
    const _Float16* base = ASm + (p * 2 + mh) * NSL + slot * 64;
#pragma unroll
    for (int kb = 0; kb < 2; ++kb) {
      int uu = (kb * 4 + grp) ^ (slot & 7);
      af[mti][kb] = *(const h16x8*)(base + uu * 8);
    }
  }
}

__device__ __forceinline__ void load_bf(const _Float16* BSm, int p, int nh,
                                        int wn, int lm, int grp, h16x8 bf[2][2]) {
#pragma unroll
  for (int nti = 0; nti < 2; ++nti) {
    int slot = wn * 32 + nti * 16 + lm;
    const _Float16* base = BSm + (p * 2 + nh) * NSL + slot * 64;
#pragma unroll
    for (int kb = 0; kb < 2; ++kb) {
      int uu = (kb * 4 + grp) ^ (slot & 7);
      bf[nti][kb] = *(const h16x8*)(base + uu * 8);
    }
  }
}

__device__ __forceinline__ void mfma_pair(f32x4 acc[8][4], const h16x8 af[4][2],
                                          const h16x8 bf0[2][2], const h16x8 bf1[2][2],
                                          int mh) {
  __builtin_amdgcn_s_setprio(1);
#pragma unroll
  for (int nti = 0; nti < 2; ++nti)
#pragma unroll
    for (int mti = 0; mti < 4; ++mti)
#pragma unroll
      for (int kb = 0; kb < 2; ++kb)
        acc[mh * 4 + mti][nti] = __builtin_amdgcn_mfma_f32_16x16x32_f16(
            af[mti][kb], bf0[nti][kb], acc[mh * 4 + mti][nti], 0, 0, 0);
#pragma unroll
  for (int nti = 0; nti < 2; ++nti)
#pragma unroll
    for (int mti = 0; mti < 4; ++mti)
#pragma unroll
      for (int kb = 0; kb < 2; ++kb)
        acc[mh * 4 + mti][2 + nti] = __builtin_amdgcn_mfma_f32_16x16x32_f16(
            af[mti][kb], bf1[nti][kb], acc[mh * 4 + mti][2 + nti], 0, 0, 0);
  __builtin_amdgcn_s_setprio(0);
}

__device__ __forceinline__ void pre_mfma() { __builtin_amdgcn_sched_barrier(0); }
__device__ __forceinline__ void phase_end() { __builtin_amdgcn_s_barrier(); }
__device__ __forceinline__ void phase_end_v6() {
  asm volatile("s_waitcnt vmcnt(6)" ::: "memory");
  __builtin_amdgcn_s_barrier();
}
__device__ __forceinline__ void phase_end_v4() {
  asm volatile("s_waitcnt vmcnt(4)" ::: "memory");
  __builtin_amdgcn_s_barrier();
}

template <typename OutT>
__device__ __forceinline__ void gemm8_body(
    const _Float16* __restrict__ A, const _Float16* __restrict__ B, OutT* __restrict__ C,
    int Klen, int lda, int ldb, int kmask, int ldc, long sA, long sB, long sC,
    float cshift, _Float16* smem) {
  _Float16* ASm = smem;
  _Float16* BSm = smem + 4 * NSL;

  const int nwgx = gridDim.x, nwgy = gridDim.y;
  const int nwg = nwgx * nwgy * gridDim.z;
  const int lin = blockIdx.x + nwgx * (blockIdx.y + nwgy * blockIdx.z);
  const int swzid = (lin & 7) * (nwg >> 3) + (lin >> 3);   // XCD-chunked (nwg%8==0)
  const int bx = swzid % nwgx;
  const int rest = swzid / nwgx;
  const int by = rest % nwgy, bz = rest / nwgy;

  const _Float16* Ab = A + (size_t)bz * sA;
  const _Float16* Bb = B + (size_t)bz * sB;
  OutT* Cb = C + (size_t)bz * sC;
  const int m0 = by * 256, n0 = bx * 256;

  const int tid = threadIdx.x, lane = tid & 63, w = tid >> 6;
  const int wm = w >> 2, wn = w & 3;
  const int lm = lane & 15, grp = lane >> 4;

  const _Float16* pAj[2];
  const _Float16* pBj[2];
#pragma unroll
  for (int j = 0; j < 2; ++j) {
    int s = (j * 8 + w) * 8 + (lane >> 3);
    int colp = ((lane & 7) ^ (s & 7)) * 8;
    int rA = (s & 63) | ((s >> 6) << 7);
    int rB = (s & 31) | ((s >> 5) << 6);
    pAj[j] = Ab + (size_t)(m0 + rA) * lda + colp;
    pBj[j] = Bb + (size_t)(n0 + rB) * ldb + colp;
  }
  const size_t hA = (size_t)64 * lda;
  const size_t hB = (size_t)32 * ldb;

#define STAGE_A(p, h, kk) do { \
    gload_lds16(pAj[0] + ((h) ? hA : 0) + (kk), ASm + ((p) * 2 + (h)) * NSL + w * 512); \
    gload_lds16(pAj[1] + ((h) ? hA : 0) + (kk), ASm + ((p) * 2 + (h)) * NSL + 4096 + w * 512); \
  } while (0)
#define STAGE_B(p, h, kk) do { \
    gload_lds16(pBj[0] + ((h) ? hB : 0) + (kk), BSm + ((p) * 2 + (h)) * NSL + w * 512); \
    gload_lds16(pBj[1] + ((h) ? hB : 0) + (kk), BSm + ((p) * 2 + (h)) * NSL + 4096 + w * 512); \
  } while (0)

  f32x4 acc[8][4] = {};
  const int NT = Klen / 64;

  STAGE_A(0, 0, 0);
  STAGE_B(0, 1, 0);
  STAGE_A(0, 1, 0);
  STAGE_B(0, 0, 0);
  STAGE_A(1, 0, 64);
  STAGE_B(1, 1, 64 & kmask);
  asm volatile("s_waitcnt vmcnt(4)" ::: "memory");
  __builtin_amdgcn_s_barrier();                                   // barrier #1

  h16x8 af[4][2], bf0[2][2], bf1[2][2];

  for (int it = 0; it < NT / 2; ++it) {                            // 4 barriers/iter
    const int t = 2 * it;
    const int kt1 = (t + 1) * 64;
    const int kt2 = ((t + 2 < NT) ? (t + 2) : (NT - 1)) * 64;
    const int kt3 = ((t + 3 < NT) ? (t + 3) : (NT - 1)) * 64;
    const int kt1b = kt1 & kmask, kt2b = kt2 & kmask, kt3b = kt3 & kmask;

    load_af(ASm, 0, 0, wm, lm, grp, af);
    load_bf(BSm, 0, 0, wn, lm, grp, bf0);
    load_bf(BSm, 0, 1, wn, lm, grp, bf1);
    STAGE_B(1, 0, kt1b);
    STAGE_A(1, 1, kt1);
    pre_mfma(); mfma_pair(acc, af, bf0, bf1, 0); phase_end();

    load_af(ASm, 0, 1, wm, lm, grp, af);
    STAGE_A(0, 0, kt2);
    STAGE_B(0, 1, kt2b);
    STAGE_B(0, 0, kt2b);
    pre_mfma(); mfma_pair(acc, af, bf0, bf1, 1);
    phase_end_v6();

    load_af(ASm, 1, 0, wm, lm, grp, af);
    load_bf(BSm, 1, 0, wn, lm, grp, bf0);
    load_bf(BSm, 1, 1, wn, lm, grp, bf1);
    STAGE_A(0, 1, kt2);
    pre_mfma(); mfma_pair(acc, af, bf0, bf1, 0); phase_end();

    load_af(ASm, 1, 1, wm, lm, grp, af);
    STAGE_A(1, 0, kt3);
    STAGE_B(1, 1, kt3b);
    pre_mfma(); mfma_pair(acc, af, bf0, bf1, 1);
    phase_end_v4();
  }

#pragma unroll
  for (int mh = 0; mh < 2; ++mh)
#pragma unroll
    for (int mti = 0; mti < 4; ++mti) {
      int row0 = m0 + wm * 128 + mh * 64 + mti * 16 + grp * 4;
#pragma unroll
      for (int nh = 0; nh < 2; ++nh)
#pragma unroll
        for (int nti = 0; nti < 2; ++nti) {
          int col = n0 + wn * 64 + nh * 32 + nti * 16 + lm;
#pragma unroll
          for (int qq = 0; qq < 4; ++qq)
            Cb[(size_t)(row0 + qq) * ldc + col] =
                (OutT)(acc[mh * 4 + mti][nh * 2 + nti][qq] + cshift);
        }
    }
#undef STAGE_A
#undef STAGE_B
}

// ============ aux-wave helpers (per-wave vmcnt/lgkm — no GEMM interference) ============

// KT transpose: one 64x64 tile per wave, private LDS region, own-wave lgkm only.
__device__ __forceinline__ void kt_phaseA(const float* __restrict__ K, _Float16* tw,
                                          int tau, int lane) {
  const int b = tau >> 9, r = tau & 511, kt = r >> 4, dt = r & 15;
  const int k0 = kt * 64, d0 = dt * 64;
  const int c4 = (lane & 15) * 4, rsel = lane >> 4;
#pragma unroll
  for (int i = 0; i < 16; ++i) {
    int kk = i * 4 + rsel;
    f4 v = *(const f4*)(K + ((size_t)b * LK + k0 + kk) * DD + d0 + c4);
#pragma unroll
    for (int j = 0; j < 4; ++j) tw[(c4 + j) * 68 + kk] = (_Float16)v[j];
  }
}
__device__ __forceinline__ void kt_phaseB(_Float16* __restrict__ KT, const _Float16* tw,
                                          int tau, int lane) {
  asm volatile("s_waitcnt lgkmcnt(0)" ::: "memory");   // own-wave ds_writes complete
  const int b = tau >> 9, r = tau & 511, kt = r >> 4, dt = r & 15;
  const int k0 = kt * 64, d0 = dt * 64;
  const int c4 = (lane & 15) * 4, rsel = lane >> 4;
#pragma unroll
  for (int i = 0; i < 16; ++i) {
    int dd = i * 4 + rsel;
    h16x4 o = *(const h16x4*)(tw + dd * 68 + c4);
    *(h16x4*)(KT + ((size_t)b * DD + d0 + dd) * LK + k0 + c4) = o;
  }
}

// ============ GEMM1 kernel: 8 GEMM waves + 2 KT-transpose waves ============

__global__ __launch_bounds__(640, 2) void gemm8_f16(
    const _Float16* __restrict__ A, const _Float16* __restrict__ B, _Float16* __restrict__ C,
    int Klen, int lda, int ldb, int kmask, int ldc, long sA, long sB, long sC,
    const float* __restrict__ Kin, _Float16* __restrict__ KT) {
  extern __shared__ _Float16 smem[];
  __shared__ _Float16 ktw[2][64 * 68];
  const int tid = threadIdx.x, w = tid >> 6;
  if (w < 8) {
    gemm8_body<_Float16>(A, B, C, Klen, lda, ldb, kmask, ldc, sA, sB, sC, -SSHIFT, smem);
  } else {
    const int aw = w - 8, lane = tid & 63;
    const int lin = blockIdx.x + gridDim.x * (blockIdx.y + gridDim.y * blockIdx.z); // 0..511
    const int nbar = 1 + (Klen >> 5);   // == 1 + 4*(NT/2)
    _Float16* tw = &ktw[aw][0];
    for (int j = 0; j < nbar; ++j) {
      if (j < 32) {
        int t = j >> 3, ph = j & 7;
        int tau = lin * 8 + aw * 4 + t;   // 512 blocks x 8 tiles = 4096 tiles
        if (ph == 0) kt_phaseA(Kin, tw, tau, lane);
        else if (ph == 4) kt_phaseB(KT, tw, tau, lane);
      }
      __builtin_amdgcn_s_barrier();
    }
  }
}

// ============ GEMM2 kernel: 8 GEMM waves + 2 attn-expansion waves ============

__global__ __launch_bounds__(640, 2) void gemm8_f32(
    const _Float16* __restrict__ A, const _Float16* __restrict__ B, float* __restrict__ C,
    int Klen, int lda, int ldb, int kmask, int ldc, long sA, long sB, long sC,
    const _Float16* __restrict__ Pw, float* __restrict__ attn) {
  extern __shared__ _Float16 smem[];
  const int tid = threadIdx.x, w = tid >> 6;
  if (w < 8) {
    gemm8_body<float>(A, B, C, Klen, lda, ldb, kmask, ldc, sA, sB, sC, 0.0f, smem);
  } else {
    const int lin = blockIdx.x + gridDim.x * (blockIdx.y + gridDim.y * blockIdx.z); // 0..255
    const int nbar = 1 + (Klen >> 5);   // 65 for Klen=2048
    const int at = tid - 512;           // 0..127
    const size_t base = (size_t)lin * 131072;   // 256 blocks x 131072 = 33.55M elems
    for (int j = 0; j < nbar; ++j) {
      if (j < 64) {
        size_t off = base + (size_t)j * 2048 + (size_t)at * 8;
        h16x8 v0 = *(const h16x8*)(Pw + off);
        h16x8 v1 = *(const h16x8*)(Pw + off + 1024);
        f4 a0, a1, b0, b1;
#pragma unroll
        for (int i = 0; i < 4; ++i) {
          a0[i] = (float)v0[i];  a1[i] = (float)v0[i + 4];
          b0[i] = (float)v1[i];  b1[i] = (float)v1[i + 4];
        }
        *(f4*)(attn + off) = a0;        *(f4*)(attn + off + 4) = a1;
        *(f4*)(attn + off + 1024) = b0; *(f4*)(attn + off + 1028) = b1;
      }
      __builtin_amdgcn_s_barrier();
    }
  }
}

// ============ softmax: fp16 shifted scores -> P fp16, in place only ============

__global__ __launch_bounds__(256) void softmax_p(_Float16* __restrict__ SP) {
  __shared__ float red[4];
  const int row = blockIdx.x;
  _Float16* pr = SP + (size_t)row * LK;
  const int t = threadIdx.x, lane = t & 63, w = t >> 6;
  h16x8 v = *(const h16x8*)(pr + t * 8);
  float x[8];
#pragma unroll
  for (int i = 0; i < 8; ++i) x[i] = (float)v[i];

  float m = x[0];
#pragma unroll
  for (int i = 1; i < 8; ++i) m = fmaxf(m, x[i]);
#pragma unroll
  for (int off = 32; off > 0; off >>= 1) m = fmaxf(m, __shfl_xor(m, off));
  if (lane == 0) red[w] = m;
  __syncthreads();
  m = fmaxf(fmaxf(red[0], red[1]), fmaxf(red[2], red[3]));
  __syncthreads();

  float e[8];
  float s = 0.f;
#pragma unroll
  for (int i = 0; i < 8; ++i) { e[i] = __expf(x[i] - m); s += e[i]; }
#pragma unroll
  for (int off = 32; off > 0; off >>= 1) s += __shfl_xor(s, off);
  if (lane == 0) red[w] = s;
  __syncthreads();
  s = red[0] + red[1] + red[2] + red[3];
  const float inv = 1.0f / s;

  h16x8 o;
#pragma unroll
  for (int i = 0; i < 8; ++i) o[i] = (_Float16)(e[i] * inv);
  *(h16x8*)(pr + t * 8) = o;
}

// ============ fp32 softmax (fallback path) ============

__global__ __launch_bounds__(256) void softmax_rows(float* __restrict__ S,
                                                    _Float16* __restrict__ P) {
  __shared__ float red[4];
  const int row = blockIdx.x;
  float* p = S + (size_t)row * LK;
  const int t = threadIdx.x;
  const int lane = t & 63, w = t >> 6;
  f4* p4 = (f4*)p;
  f4 v0 = p4[t], v1 = p4[t + 256];

  float m = fmaxf(fmaxf(fmaxf(v0[0], v0[1]), fmaxf(v0[2], v0[3])),
                  fmaxf(fmaxf(v1[0], v1[1]), fmaxf(v1[2], v1[3])));
#pragma unroll
  for (int off = 32; off > 0; off >>= 1) m = fmaxf(m, __shfl_xor(m, off));
  if (lane == 0) red[w] = m;
  __syncthreads();
  m = fmaxf(fmaxf(red[0], red[1]), fmaxf(red[2], red[3]));
  __syncthreads();

  f4 e0, e1;
  float s = 0.f;
#pragma unroll
  for (int i = 0; i < 4; ++i) { e0[i] = __expf(v0[i] - m); s += e0[i]; }
#pragma unroll
  for (int i = 0; i < 4; ++i) { e1[i] = __expf(v1[i] - m); s += e1[i]; }
#pragma unroll
  for (int off = 32; off > 0; off >>= 1) s += __shfl_xor(s, off);
  if (lane == 0) red[w] = s;
  __syncthreads();
  s = red[0] + red[1] + red[2] + red[3];
  float inv = 1.0f / s;
  e0 *= inv; e1 *= inv;
  p4[t] = e0; p4[t + 256] = e1;
  if (P) {
    h16x4 a, bb;
#pragma unroll
    for (int i = 0; i < 4; ++i) { a[i] = (_Float16)e0[i]; bb[i] = (_Float16)e1[i]; }
    _Float16* pr = P + (size_t)row * LK;
    *(h16x4*)(pr + t * 4) = a;
    *(h16x4*)(pr + 1024 + t * 4) = bb;
  }
}

// ============ fallback path (split-bf16, no workspace) ============

__device__ __forceinline__ unsigned int f2bf_bits(float x) {
  unsigned int u = __float_as_uint(x);
  return (u + 0x7fffu + ((u >> 16) & 1u)) >> 16;
}
__device__ __forceinline__ float bf2f(unsigned int h) { return __uint_as_float(h << 16); }
__device__ __forceinline__ void hilo4(const f4 v, unsigned long long& ph, unsigned long long& pl) {
  unsigned int h[4], l[4];
#pragma unroll
  for (int i = 0; i < 4; ++i) {
    h[i] = f2bf_bits(v[i]);
    float rr = v[i] - bf2f(h[i]);
    l[i] = f2bf_bits(rr);
  }
  ph = (unsigned long long)h[0] | ((unsigned long long)h[1] << 16) |
       ((unsigned long long)h[2] << 32) | ((unsigned long long)h[3] << 48);
  pl = (unsigned long long)l[0] | ((unsigned long long)l[1] << 16) |
       ((unsigned long long)l[2] << 32) | ((unsigned long long)l[3] << 48);
}
__device__ __forceinline__ unsigned long long pack4bf(float a, float b, float c, float d) {
  return (unsigned long long)f2bf_bits(a) | ((unsigned long long)f2bf_bits(b) << 16) |
         ((unsigned long long)f2bf_bits(c) << 32) | ((unsigned long long)f2bf_bits(d) << 48);
}
__device__ __forceinline__ s16x8 mkfrag(unsigned long long u0, unsigned long long u1) {
  u64x2_t t; t[0] = u0; t[1] = u1;
  return __builtin_bit_cast(s16x8, t);
}
__device__ __forceinline__ f32x4 mfma16b(s16x8 a, s16x8 b, f32x4 c) {
  return __builtin_amdgcn_mfma_f32_16x16x32_bf16(a, b, c, 0, 0, 0);
}

__global__ __launch_bounds__(256) void gemm1_scores(
    const float* __restrict__ Q, const float* __restrict__ K, float* __restrict__ S) {
  __shared__ unsigned long long Ah[128 * 8], Al[128 * 8], Bh[128 * 8], Bl[128 * 8];
  const int b = blockIdx.z;
  const float* Qb = Q + (size_t)b * LQ * DD;
  const float* Kb = K + (size_t)b * LK * DD;
  float* Sb = S + (size_t)b * LQ * LK;
  const int m0 = blockIdx.y * 128, n0 = blockIdx.x * 128;
  const int t = threadIdx.x;
  const int lane = t & 63, w = t >> 6;
  const int wr = (w >> 1) * 64, wc = (w & 1) * 64;
  const int lm = lane & 15, grp = lane >> 4;
  f32x4 acc[4][4] = {};
  const int r = t >> 1, hf = t & 1;
  const int sw_st = ((r >> 1) ^ (r >> 4)) & 7;
  const f4* srcA = (const f4*)(Qb + (size_t)(m0 + r) * DD) + hf * 4;
  const f4* srcB = (const f4*)(Kb + (size_t)(n0 + r) * DD) + hf * 4;
  for (int k0 = 0; k0 < DD; k0 += 32) {
#pragma unroll
    for (int u = 0; u < 4; ++u) {
      f4 v = srcA[u];
      unsigned long long ph, pl;
      hilo4(v, ph, pl);
      int idx = r * 8 + ((hf * 4 + u) ^ sw_st);
      Ah[idx] = ph; Al[idx] = pl;
    }
#pragma unroll
    for (int u = 0; u < 4; ++u) {
      f4 v = srcB[u];
      unsigned long long ph, pl;
      hilo4(v, ph, pl);
      int idx = r * 8 + ((hf * 4 + u) ^ sw_st);
      Bh[idx] = ph; Bl[idx] = pl;
    }
    srcA += 8; srcB += 8;
    __syncthreads();
    s16x8 afh[4], afl[4];
#pragma unroll
    for (int mt = 0; mt < 4; ++mt) {
      int row = wr + mt * 16 + lm;
      int sw = ((row >> 1) ^ (row >> 4)) & 7;
      int ua = (2 * grp) ^ sw;
      int base = row * 8;
      afh[mt] = mkfrag(Ah[base + ua], Ah[base + (ua ^ 1)]);
      afl[mt] = mkfrag(Al[base + ua], Al[base + (ua ^ 1)]);
    }
#pragma unroll
    for (int nt = 0; nt < 4; ++nt) {
      int row = wc + nt * 16 + lm;
      int sw = ((row >> 1) ^ (row >> 4)) & 7;
      int ua = (2 * grp) ^ sw;
      int base = row * 8;
      s16x8 bfh = mkfrag(Bh[base + ua], Bh[base + (ua ^ 1)]);
      s16x8 bfl = mkfrag(Bl[base + ua], Bl[base + (ua ^ 1)]);
#pragma unroll
      for (int mt = 0; mt < 4; ++mt) {
        acc[mt][nt] = mfma16b(afh[mt], bfh, acc[mt][nt]);
        acc[mt][nt] = mfma16b(afh[mt], bfl, acc[mt][nt]);
        acc[mt][nt] = mfma16b(afl[mt], bfh, acc[mt][nt]);
      }
    }
    __syncthreads();
  }
#pragma unroll
  for (int mt = 0; mt < 4; ++mt) {
    int rowb = m0 + wr + mt * 16 + grp * 4;
#pragma unroll
    for (int nt = 0; nt < 4; ++nt) {
      int col = n0 + wc + nt * 16 + lm;
#pragma unroll
      for (int q = 0; q < 4; ++q)
        Sb[(size_t)(rowb + q) * LK + col] = acc[mt][nt][q];
    }
  }
}

__global__ __launch_bounds__(256) void gemm2_ctx(
    const float* __restrict__ P, const float* __restrict__ K, float* __restrict__ C) {
  __shared__ unsigned long long As[128 * 8], Bs[128 * 8];
  const int b = blockIdx.z;
  const float* Pb = P + (size_t)b * LQ * LK;
  const float* Kb = K + (size_t)b * LK * DD;
  float* Cb = C + (size_t)b * LQ * DD;
  const int m0 = blockIdx.y * 128, n0 = blockIdx.x * 128;
  const int t = threadIdx.x, lane = t & 63, w = t >> 6;
  const int wr = (w >> 1) * 64, wc = (w & 1) * 64;
  const int lm = lane & 15, grp = lane >> 4;
  f32x4 acc[4][4] = {};
  const int r = t >> 1, hf = t & 1;
  const int sw_a = ((r >> 1) ^ (r >> 4)) & 7;
  const f4* srcA = (const f4*)(Pb + (size_t)(m0 + r) * LK) + hf * 4;
  const int ka = t >> 5, bi = t & 31;
  const float* srcB0 = Kb + (size_t)(4 * ka) * DD + n0 + 4 * bi;
  for (int k0 = 0; k0 < LK; k0 += 32) {
#pragma unroll
    for (int u = 0; u < 4; ++u) {
      f4 v = srcA[u];
      As[r * 8 + ((hf * 4 + u) ^ sw_a)] = pack4bf(v[0], v[1], v[2], v[3]);
    }
    srcA += 8;
    const float* sB = srcB0 + (size_t)k0 * DD;
    f4 rv[4];
#pragma unroll
    for (int rr = 0; rr < 4; ++rr) rv[rr] = *(const f4*)(sB + (size_t)rr * DD);
#pragma unroll
    for (int q = 0; q < 4; ++q) {
      int n = 4 * bi + q;
      int sw = ((n >> 1) ^ (n >> 4)) & 7;
      Bs[n * 8 + (ka ^ sw)] = pack4bf(rv[0][q], rv[1][q], rv[2][q], rv[3][q]);
    }
    __syncthreads();
    s16x8 af2[4];
#pragma unroll
    for (int mt = 0; mt < 4; ++mt) {
      int row = wr + mt * 16 + lm;
      int sw = ((row >> 1) ^ (row >> 4)) & 7;
      int ua = (2 * grp) ^ sw;
      af2[mt] = mkfrag(As[row * 8 + ua], As[row * 8 + (ua ^ 1)]);
    }
#pragma unroll
    for (int nt = 0; nt < 4; ++nt) {
      int row = wc + nt * 16 + lm;
      int sw = ((row >> 1) ^ (row >> 4)) & 7;
      int ua = (2 * grp) ^ sw;
      s16x8 bf = mkfrag(Bs[row * 8 + ua], Bs[row * 8 + (ua ^ 1)]);
#pragma unroll
      for (int mt = 0; mt < 4; ++mt)
        acc[mt][nt] = mfma16b(af2[mt], bf, acc[mt][nt]);
    }
    __syncthreads();
  }
#pragma unroll
  for (int mt = 0; mt < 4; ++mt) {
    int rowb = m0 + wr + mt * 16 + grp * 4;
#pragma unroll
    for (int nt = 0; nt < 4; ++nt) {
      int col = n0 + wc + nt * 16 + lm;
#pragma unroll
      for (int q = 0; q < 4; ++q)
        Cb[(size_t)(rowb + q) * DD + col] = acc[mt][nt][q];
    }
  }
}

// ============ launch ============

extern "C" void kernel_launch(void* const* d_in, const int* in_sizes, int n_in,
                              void* d_out, int out_size, void* d_ws, size_t ws_size,
                              hipStream_t stream) {
  const float* Q = (const float*)d_in[0];   // "output": (B, Lq, D)
  const float* K = (const float*)d_in[1];   // "inputs": (B, Lk, D)
  float* ctx  = (float*)d_out;                           // (B, Lq, D)
  float* attn = (float*)d_out + (size_t)NB * LQ * DD;    // (B, Lq, Lk)

  const size_t nQh = (size_t)NB * LQ * DD;     // Qh fp16
  const size_t nKh = (size_t)NB * LK * DD;     // Kh fp16
  const size_t nKT = (size_t)NB * DD * LK;     // K^T fp16
  const size_t nPw = (size_t)NB * LQ * LK;     // scores fp16 -> P fp16 (in place)
  const size_t need = (nQh + nKh + nKT + nPw) * sizeof(_Float16);

  if (ws_size >= need) {
    _Float16* Qh = (_Float16*)d_ws;
    _Float16* Kh = Qh + nQh;
    _Float16* KT = Kh + nKh;
    _Float16* Pw = KT + nKT;

    (void)hipFuncSetAttribute((const void*)gemm8_f16,
                              hipFuncAttributeMaxDynamicSharedMemorySize, 131072);
    (void)hipFuncSetAttribute((const void*)gemm8_f32,
                              hipFuncAttributeMaxDynamicSharedMemorySize, 131072);

    conv_flat<<<2048, 256, 0, stream>>>(Q, K, Qh, Kh);

    // S-125 (fp16, into Pw) + aux waves build KT under the GEMM
    gemm8_f16<<<dim3(LK / 256, LQ / 256, NB), 640, 131072, stream>>>(
        Qh, Kh, Pw, 1024, 1024, 1024, 1023, LK,
        (long)LQ * DD, (long)LK * DD, (long)LQ * LK, K, KT);

    // softmax in place on Pw (fp16 only)
    softmax_p<<<dim3(NB * LQ), 256, 0, stream>>>(Pw);

    // ctx = Pw * KT^T + aux waves expand attn fp32 from Pw under the GEMM
    gemm8_f32<<<dim3(DD / 256, LQ / 256, NB), 640, 131072, stream>>>(
        Pw, KT, ctx, 2048, 2048, 2048, 2047, DD,
        (long)LQ * LK, (long)DD * LK, (long)LQ * DD, Pw, attn);
  } else {
    gemm1_scores<<<dim3(LK / 128, LQ / 128, NB), 256, 0, stream>>>(Q, K, attn);
    softmax_rows<<<dim3(NB * LQ), 256, 0, stream>>>(attn, nullptr);
    gemm2_ctx<<<dim3(DD / 128, LQ / 128, NB), 256, 0, stream>>>(attn, K, ctx);
  }
}

// Round 10
// 230.827 us; speedup vs baseline: 4.7803x; 4.7803x over previous
//
#include <hip/hip_runtime.h>

#define LQ 2048
#define LK 2048
#define DD 1024
#define NB 8
#define NSL 8192   // elements per (dbuf,half) region: 128 slots x 64 cols
#define SSHIFT 125.0f   // row-uniform score shift: centers high-p scores near 0 for fp16 storage

typedef __attribute__((ext_vector_type(4))) float f4;
typedef __attribute__((ext_vector_type(4))) float f32x4;
typedef __attribute__((ext_vector_type(8))) short s16x8;
typedef __attribute__((ext_vector_type(8))) _Float16 h16x8;
typedef __attribute__((ext_vector_type(4))) _Float16 h16x4;
typedef __attribute__((ext_vector_type(2))) unsigned long long u64x2_t;

__device__ __forceinline__ void gload_lds16(const _Float16* g, const _Float16* l) {
  __builtin_amdgcn_global_load_lds((const __attribute__((address_space(1))) void*)g,
                                   (__attribute__((address_space(3))) void*)l, 16, 0, 0);
}

// ============ fused conversions ============
// grid (64, 16, NB): x<32 -> K-conv (Kh + KT), x>=32 -> Q-conv (Qh)

__global__ __launch_bounds__(256) void conv_all(const float* __restrict__ Q,
                                                const float* __restrict__ K,
                                                _Float16* __restrict__ Qh,
                                                _Float16* __restrict__ Kh,
                                                _Float16* __restrict__ KT) {
  __shared__ _Float16 tile[64][66];
  const int b = blockIdx.z;
  const int t = threadIdx.x, tr = t >> 4, tc = t & 15;
  if (blockIdx.x >= 32) {
    const int r0 = (blockIdx.x - 32) * 64, d0 = blockIdx.y * 64;
    const float* Qb = Q + ((size_t)b * LQ + r0) * DD + d0;
    _Float16* Qo = Qh + ((size_t)b * LQ + r0) * DD + d0;
#pragma unroll
    for (int i = 0; i < 4; ++i) {
      int rr = tr + i * 16;
      f4 v = *(const f4*)(Qb + (size_t)rr * DD + tc * 4);
      h16x4 h;
#pragma unroll
      for (int j = 0; j < 4; ++j) h[j] = (_Float16)v[j];
      *(h16x4*)(Qo + (size_t)rr * DD + tc * 4) = h;
    }
  } else {
    const int k0 = blockIdx.x * 64, d0 = blockIdx.y * 64;
#pragma unroll
    for (int i = 0; i < 4; ++i) {
      int kk = tr + i * 16;
      f4 v = *(const f4*)(K + ((size_t)b * LK + k0 + kk) * DD + d0 + tc * 4);
      h16x4 h;
#pragma unroll
      for (int j = 0; j < 4; ++j) { h[j] = (_Float16)v[j]; tile[tc * 4 + j][kk] = h[j]; }
      *(h16x4*)(Kh + ((size_t)b * LK + k0 + kk) * DD + d0 + tc * 4) = h;
    }
    __syncthreads();
#pragma unroll
    for (int i = 0; i < 4; ++i) {
      int dd = tr + i * 16;
      h16x4 o;
#pragma unroll
      for (int j = 0; j < 4; ++j) o[j] = tile[dd][tc * 4 + j];
      *(h16x4*)(KT + ((size_t)b * DD + d0 + dd) * LK + k0 + tc * 4) = o;
    }
  }
}

// ============ 256x256 4-phase GEMM: C = A * B^T (round-8 verified core) ============
// 512 threads = 8 waves (2M x 4N); per-wave C = 128x64; BK=64, double-buffered
// halves; 4 phases of 32 MFMA per 2-K-tile iter; counted vmcnt; strictly-after
// staging ledger. No XCD swizzle: working sets are L3-resident (m160: swizzle
// costs ~2% when L3-fit).

__device__ __forceinline__ void load_af(const _Float16* ASm, int p, int mh,
                                        int wm, int lm, int grp, h16x8 af[4][2]) {
#pragma unroll
  for (int mti = 0; mti < 4; ++mti) {
    int slot = wm * 64 + mti * 16 + lm;
    const _Float16* base = ASm + (p * 2 + mh) * NSL + slot * 64;
#pragma unroll
    for (int kb = 0; kb < 2; ++kb) {
      int uu = (kb * 4 + grp) ^ (slot & 7);
      af[mti][kb] = *(const h16x8*)(base + uu * 8);
    }
  }
}

__device__ __forceinline__ void load_bf(const _Float16* BSm, int p, int nh,
                                        int wn, int lm, int grp, h16x8 bf[2][2]) {
#pragma unroll
  for (int nti = 0; nti < 2; ++nti) {
    int slot = wn * 32 + nti * 16 + lm;
    const _Float16* base = BSm + (p * 2 + nh) * NSL + slot * 64;
#pragma unroll
    for (int kb = 0; kb < 2; ++kb) {
      int uu = (kb * 4 + grp) ^ (slot & 7);
      bf[nti][kb] = *(const h16x8*)(base + uu * 8);
    }
  }
}

__device__ __forceinline__ void mfma_pair(f32x4 acc[8][4], const h16x8 af[4][2],
                                          const h16x8 bf0[2][2], const h16x8 bf1[2][2],
                                          int mh) {
  __builtin_amdgcn_s_setprio(1);
#pragma unroll
  for (int nti = 0; nti < 2; ++nti)
#pragma unroll
    for (int mti = 0; mti < 4; ++mti)
#pragma unroll
      for (int kb = 0; kb < 2; ++kb)
        acc[mh * 4 + mti][nti] = __builtin_amdgcn_mfma_f32_16x16x32_f16(
            af[mti][kb], bf0[nti][kb], acc[mh * 4 + mti][nti], 0, 0, 0);
#pragma unroll
  for (int nti = 0; nti < 2; ++nti)
#pragma unroll
    for (int mti = 0; mti < 4; ++mti)
#pragma unroll
      for (int kb = 0; kb < 2; ++kb)
        acc[mh * 4 + mti][2 + nti] = __builtin_amdgcn_mfma_f32_16x16x32_f16(
            af[mti][kb], bf1[nti][kb], acc[mh * 4 + mti][2 + nti], 0, 0, 0);
  __builtin_amdgcn_s_setprio(0);
}

__device__ __forceinline__ void pre_mfma() { __builtin_amdgcn_sched_barrier(0); }
__device__ __forceinline__ void phase_end() { __builtin_amdgcn_s_barrier(); }
__device__ __forceinline__ void phase_end_v6() {
  asm volatile("s_waitcnt vmcnt(6)" ::: "memory");
  __builtin_amdgcn_s_barrier();
}
__device__ __forceinline__ void phase_end_v4() {
  asm volatile("s_waitcnt vmcnt(4)" ::: "memory");
  __builtin_amdgcn_s_barrier();
}

template <typename OutT>
__device__ __forceinline__ void gemm8_body(
    const _Float16* __restrict__ A, const _Float16* __restrict__ B, OutT* __restrict__ C,
    int Klen, int lda, int ldb, int kmask, int ldc, long sA, long sB, long sC,
    float cshift, _Float16* smem) {
  _Float16* ASm = smem;
  _Float16* BSm = smem + 4 * NSL;

  const int bx = blockIdx.x, by = blockIdx.y, bz = blockIdx.z;

  const _Float16* Ab = A + (size_t)bz * sA;
  const _Float16* Bb = B + (size_t)bz * sB;
  OutT* Cb = C + (size_t)bz * sC;
  const int m0 = by * 256, n0 = bx * 256;

  const int tid = threadIdx.x, lane = tid & 63, w = tid >> 6;
  const int wm = w >> 2, wn = w & 3;
  const int lm = lane & 15, grp = lane >> 4;

  const _Float16* pAj[2];
  const _Float16* pBj[2];
#pragma unroll
  for (int j = 0; j < 2; ++j) {
    int s = (j * 8 + w) * 8 + (lane >> 3);
    int colp = ((lane & 7) ^ (s & 7)) * 8;
    int rA = (s & 63) | ((s >> 6) << 7);
    int rB = (s & 31) | ((s >> 5) << 6);
    pAj[j] = Ab + (size_t)(m0 + rA) * lda + colp;
    pBj[j] = Bb + (size_t)(n0 + rB) * ldb + colp;
  }
  const size_t hA = (size_t)64 * lda;
  const size_t hB = (size_t)32 * ldb;

#define STAGE_A(p, h, kk) do { \
    gload_lds16(pAj[0] + ((h) ? hA : 0) + (kk), ASm + ((p) * 2 + (h)) * NSL + w * 512); \
    gload_lds16(pAj[1] + ((h) ? hA : 0) + (kk), ASm + ((p) * 2 + (h)) * NSL + 4096 + w * 512); \
  } while (0)
#define STAGE_B(p, h, kk) do { \
    gload_lds16(pBj[0] + ((h) ? hB : 0) + (kk), BSm + ((p) * 2 + (h)) * NSL + w * 512); \
    gload_lds16(pBj[1] + ((h) ? hB : 0) + (kk), BSm + ((p) * 2 + (h)) * NSL + 4096 + w * 512); \
  } while (0)

  f32x4 acc[8][4] = {};
  const int NT = Klen / 64;

  STAGE_A(0, 0, 0);
  STAGE_B(0, 1, 0);
  STAGE_A(0, 1, 0);
  STAGE_B(0, 0, 0);
  STAGE_A(1, 0, 64);
  STAGE_B(1, 1, 64 & kmask);
  asm volatile("s_waitcnt vmcnt(4)" ::: "memory");
  __builtin_amdgcn_s_barrier();

  h16x8 af[4][2], bf0[2][2], bf1[2][2];

  for (int it = 0; it < NT / 2; ++it) {
    const int t = 2 * it;
    const int kt1 = (t + 1) * 64;
    const int kt2 = ((t + 2 < NT) ? (t + 2) : (NT - 1)) * 64;
    const int kt3 = ((t + 3 < NT) ? (t + 3) : (NT - 1)) * 64;
    const int kt1b = kt1 & kmask, kt2b = kt2 & kmask, kt3b = kt3 & kmask;

    // P1: tile t (buffer 0), quads (0,0),(0,1)
    load_af(ASm, 0, 0, wm, lm, grp, af);
    load_bf(BSm, 0, 0, wn, lm, grp, bf0);
    load_bf(BSm, 0, 1, wn, lm, grp, bf1);
    STAGE_B(1, 0, kt1b);
    STAGE_A(1, 1, kt1);
    pre_mfma(); mfma_pair(acc, af, bf0, bf1, 0); phase_end();

    // P2: quads (1,0),(1,1) — bf0/bf1 reused from registers
    load_af(ASm, 0, 1, wm, lm, grp, af);
    STAGE_A(0, 0, kt2);
    STAGE_B(0, 1, kt2b);
    STAGE_B(0, 0, kt2b);
    pre_mfma(); mfma_pair(acc, af, bf0, bf1, 1);
    phase_end_v6();

    // P3: tile t+1 (buffer 1), quads (0,0),(0,1)
    load_af(ASm, 1, 0, wm, lm, grp, af);
    load_bf(BSm, 1, 0, wn, lm, grp, bf0);
    load_bf(BSm, 1, 1, wn, lm, grp, bf1);
    STAGE_A(0, 1, kt2);
    pre_mfma(); mfma_pair(acc, af, bf0, bf1, 0); phase_end();

    // P4: quads (1,0),(1,1)
    load_af(ASm, 1, 1, wm, lm, grp, af);
    STAGE_A(1, 0, kt3);
    STAGE_B(1, 1, kt3b);
    pre_mfma(); mfma_pair(acc, af, bf0, bf1, 1);
    phase_end_v4();
  }

#pragma unroll
  for (int mh = 0; mh < 2; ++mh)
#pragma unroll
    for (int mti = 0; mti < 4; ++mti) {
      int row0 = m0 + wm * 128 + mh * 64 + mti * 16 + grp * 4;
#pragma unroll
      for (int nh = 0; nh < 2; ++nh)
#pragma unroll
        for (int nti = 0; nti < 2; ++nti) {
          int col = n0 + wn * 64 + nh * 32 + nti * 16 + lm;
#pragma unroll
          for (int qq = 0; qq < 4; ++qq)
            Cb[(size_t)(row0 + qq) * ldc + col] =
                (OutT)(acc[mh * 4 + mti][nh * 2 + nti][qq] + cshift);
        }
    }
#undef STAGE_A
#undef STAGE_B
}

__global__ __launch_bounds__(512, 2) void gemm8_f32(
    const _Float16* __restrict__ A, const _Float16* __restrict__ B, float* __restrict__ C,
    int Klen, int lda, int ldb, int kmask, int ldc, long sA, long sB, long sC) {
  extern __shared__ _Float16 smem[];
  gemm8_body<float>(A, B, C, Klen, lda, ldb, kmask, ldc, sA, sB, sC, 0.0f, smem);
}

__global__ __launch_bounds__(512, 2) void gemm8_f16(
    const _Float16* __restrict__ A, const _Float16* __restrict__ B, _Float16* __restrict__ C,
    int Klen, int lda, int ldb, int kmask, int ldc, long sA, long sB, long sC) {
  extern __shared__ _Float16 smem[];
  gemm8_body<_Float16>(A, B, C, Klen, lda, ldb, kmask, ldc, sA, sB, sC, -SSHIFT, smem);
}

// ============ softmax (fp16 scores in-place -> P fp16; attn fp32 out) ============

__global__ __launch_bounds__(256) void softmax_f16(_Float16* __restrict__ SP,
                                                   float* __restrict__ A) {
  __shared__ float red[4];
  const int row = blockIdx.x;
  _Float16* pr = SP + (size_t)row * LK;
  const int t = threadIdx.x, lane = t & 63, w = t >> 6;
  h16x8 v = *(const h16x8*)(pr + t * 8);
  float x[8];
#pragma unroll
  for (int i = 0; i < 8; ++i) x[i] = (float)v[i];

  float m = x[0];
#pragma unroll
  for (int i = 1; i < 8; ++i) m = fmaxf(m, x[i]);
#pragma unroll
  for (int off = 32; off > 0; off >>= 1) m = fmaxf(m, __shfl_xor(m, off));
  if (lane == 0) red[w] = m;
  __syncthreads();
  m = fmaxf(fmaxf(red[0], red[1]), fmaxf(red[2], red[3]));
  __syncthreads();

  float e[8];
  float s = 0.f;
#pragma unroll
  for (int i = 0; i < 8; ++i) { e[i] = __expf(x[i] - m); s += e[i]; }
#pragma unroll
  for (int off = 32; off > 0; off >>= 1) s += __shfl_xor(s, off);
  if (lane == 0) red[w] = s;
  __syncthreads();
  s = red[0] + red[1] + red[2] + red[3];
  const float inv = 1.0f / s;

  f4 a0, a1;
  h16x8 o;
#pragma unroll
  for (int i = 0; i < 8; ++i) {
    float y = e[i] * inv;
    if (i < 4) a0[i] = y; else a1[i - 4] = y;
    o[i] = (_Float16)y;
  }
  float* ar = A + (size_t)row * LK + t * 8;
  *(f4*)ar = a0;
  *(f4*)(ar + 4) = a1;
  *(h16x8*)(pr + t * 8) = o;
}

// ============ fp32 softmax (fallback path) ============

__global__ __launch_bounds__(256) void softmax_rows(float* __restrict__ S,
                                                    _Float16* __restrict__ P) {
  __shared__ float red[4];
  const int row = blockIdx.x;
  float* p = S + (size_t)row * LK;
  const int t = threadIdx.x;
  const int lane = t & 63, w = t >> 6;
  f4* p4 = (f4*)p;
  f4 v0 = p4[t], v1 = p4[t + 256];

  float m = fmaxf(fmaxf(fmaxf(v0[0], v0[1]), fmaxf(v0[2], v0[3])),
                  fmaxf(fmaxf(v1[0], v1[1]), fmaxf(v1[2], v1[3])));
#pragma unroll
  for (int off = 32; off > 0; off >>= 1) m = fmaxf(m, __shfl_xor(m, off));
  if (lane == 0) red[w] = m;
  __syncthreads();
  m = fmaxf(fmaxf(red[0], red[1]), fmaxf(red[2], red[3]));
  __syncthreads();

  f4 e0, e1;
  float s = 0.f;
#pragma unroll
  for (int i = 0; i < 4; ++i) { e0[i] = __expf(v0[i] - m); s += e0[i]; }
#pragma unroll
  for (int i = 0; i < 4; ++i) { e1[i] = __expf(v1[i] - m); s += e1[i]; }
#pragma unroll
  for (int off = 32; off > 0; off >>= 1) s += __shfl_xor(s, off);
  if (lane == 0) red[w] = s;
  __syncthreads();
  s = red[0] + red[1] + red[2] + red[3];
  float inv = 1.0f / s;
  e0 *= inv; e1 *= inv;
  p4[t] = e0; p4[t + 256] = e1;
  if (P) {
    h16x4 a, bb;
#pragma unroll
    for (int i = 0; i < 4; ++i) { a[i] = (_Float16)e0[i]; bb[i] = (_Float16)e1[i]; }
    _Float16* pr = P + (size_t)row * LK;
    *(h16x4*)(pr + t * 4) = a;
    *(h16x4*)(pr + 1024 + t * 4) = bb;
  }
}

// ============ fallback path (split-bf16, no workspace) ============

__device__ __forceinline__ unsigned int f2bf_bits(float x) {
  unsigned int u = __float_as_uint(x);
  return (u + 0x7fffu + ((u >> 16) & 1u)) >> 16;
}
__device__ __forceinline__ float bf2f(unsigned int h) { return __uint_as_float(h << 16); }
__device__ __forceinline__ void hilo4(const f4 v, unsigned long long& ph, unsigned long long& pl) {
  unsigned int h[4], l[4];
#pragma unroll
  for (int i = 0; i < 4; ++i) {
    h[i] = f2bf_bits(v[i]);
    float rr = v[i] - bf2f(h[i]);
    l[i] = f2bf_bits(rr);
  }
  ph = (unsigned long long)h[0] | ((unsigned long long)h[1] << 16) |
       ((unsigned long long)h[2] << 32) | ((unsigned long long)h[3] << 48);
  pl = (unsigned long long)l[0] | ((unsigned long long)l[1] << 16) |
       ((unsigned long long)l[2] << 32) | ((unsigned long long)l[3] << 48);
}
__device__ __forceinline__ unsigned long long pack4bf(float a, float b, float c, float d) {
  return (unsigned long long)f2bf_bits(a) | ((unsigned long long)f2bf_bits(b) << 16) |
         ((unsigned long long)f2bf_bits(c) << 32) | ((unsigned long long)f2bf_bits(d) << 48);
}
__device__ __forceinline__ s16x8 mkfrag(unsigned long long u0, unsigned long long u1) {
  u64x2_t t; t[0] = u0; t[1] = u1;
  return __builtin_bit_cast(s16x8, t);
}
__device__ __forceinline__ f32x4 mfma16b(s16x8 a, s16x8 b, f32x4 c) {
  return __builtin_amdgcn_mfma_f32_16x16x32_bf16(a, b, c, 0, 0, 0);
}

__global__ __launch_bounds__(256) void gemm1_scores(
    const float* __restrict__ Q, const float* __restrict__ K, float* __restrict__ S) {
  __shared__ unsigned long long Ah[128 * 8], Al[128 * 8], Bh[128 * 8], Bl[128 * 8];
  const int b = blockIdx.z;
  const float* Qb = Q + (size_t)b * LQ * DD;
  const float* Kb = K + (size_t)b * LK * DD;
  float* Sb = S + (size_t)b * LQ * LK;
  const int m0 = blockIdx.y * 128, n0 = blockIdx.x * 128;
  const int t = threadIdx.x;
  const int lane = t & 63, w = t >> 6;
  const int wr = (w >> 1) * 64, wc = (w & 1) * 64;
  const int lm = lane & 15, grp = lane >> 4;
  f32x4 acc[4][4] = {};
  const int r = t >> 1, hf = t & 1;
  const int sw_st = ((r >> 1) ^ (r >> 4)) & 7;
  const f4* srcA = (const f4*)(Qb + (size_t)(m0 + r) * DD) + hf * 4;
  const f4* srcB = (const f4*)(Kb + (size_t)(n0 + r) * DD) + hf * 4;
  for (int k0 = 0; k0 < DD; k0 += 32) {
#pragma unroll
    for (int u = 0; u < 4; ++u) {
      f4 v = srcA[u];
      unsigned long long ph, pl;
      hilo4(v, ph, pl);
      int idx = r * 8 + ((hf * 4 + u) ^ sw_st);
      Ah[idx] = ph; Al[idx] = pl;
    }
#pragma unroll
    for (int u = 0; u < 4; ++u) {
      f4 v = srcB[u];
      unsigned long long ph, pl;
      hilo4(v, ph, pl);
      int idx = r * 8 + ((hf * 4 + u) ^ sw_st);
      Bh[idx] = ph; Bl[idx] = pl;
    }
    srcA += 8; srcB += 8;
    __syncthreads();
    s16x8 afh[4], afl[4];
#pragma unroll
    for (int mt = 0; mt < 4; ++mt) {
      int row = wr + mt * 16 + lm;
      int sw = ((row >> 1) ^ (row >> 4)) & 7;
      int ua = (2 * grp) ^ sw;
      int base = row * 8;
      afh[mt] = mkfrag(Ah[base + ua], Ah[base + (ua ^ 1)]);
      afl[mt] = mkfrag(Al[base + ua], Al[base + (ua ^ 1)]);
    }
#pragma unroll
    for (int nt = 0; nt < 4; ++nt) {
      int row = wc + nt * 16 + lm;
      int sw = ((row >> 1) ^ (row >> 4)) & 7;
      int ua = (2 * grp) ^ sw;
      int base = row * 8;
      s16x8 bfh = mkfrag(Bh[base + ua], Bh[base + (ua ^ 1)]);
      s16x8 bfl = mkfrag(Bl[base + ua], Bl[base + (ua ^ 1)]);
#pragma unroll
      for (int mt = 0; mt < 4; ++mt) {
        acc[mt][nt] = mfma16b(afh[mt], bfh, acc[mt][nt]);
        acc[mt][nt] = mfma16b(afh[mt], bfl, acc[mt][nt]);
        acc[mt][nt] = mfma16b(afl[mt], bfh, acc[mt][nt]);
      }
    }
    __syncthreads();
  }
#pragma unroll
  for (int mt = 0; mt < 4; ++mt) {
    int rowb = m0 + wr + mt * 16 + grp * 4;
#pragma unroll
    for (int nt = 0; nt < 4; ++nt) {
      int col = n0 + wc + nt * 16 + lm;
#pragma unroll
      for (int q = 0; q < 4; ++q)
        Sb[(size_t)(rowb + q) * LK + col] = acc[mt][nt][q];
    }
  }
}

__global__ __launch_bounds__(256) void gemm2_ctx(
    const float* __restrict__ P, const float* __restrict__ K, float* __restrict__ C) {
  __shared__ unsigned long long As[128 * 8], Bs[128 * 8];
  const int b = blockIdx.z;
  const float* Pb = P + (size_t)b * LQ * LK;
  const float* Kb = K + (size_t)b * LK * DD;
  float* Cb = C + (size_t)b * LQ * DD;
  const int m0 = blockIdx.y * 128, n0 = blockIdx.x * 128;
  const int t = threadIdx.x, lane = t & 63, w = t >> 6;
  const int wr = (w >> 1) * 64, wc = (w & 1) * 64;
  const int lm = lane & 15, grp = lane >> 4;
  f32x4 acc[4][4] = {};
  const int r = t >> 1, hf = t & 1;
  const int sw_a = ((r >> 1) ^ (r >> 4)) & 7;
  const f4* srcA = (const f4*)(Pb + (size_t)(m0 + r) * LK) + hf * 4;
  const int ka = t >> 5, bi = t & 31;
  const float* srcB0 = Kb + (size_t)(4 * ka) * DD + n0 + 4 * bi;
  for (int k0 = 0; k0 < LK; k0 += 32) {
#pragma unroll
    for (int u = 0; u < 4; ++u) {
      f4 v = srcA[u];
      As[r * 8 + ((hf * 4 + u) ^ sw_a)] = pack4bf(v[0], v[1], v[2], v[3]);
    }
    srcA += 8;
    const float* sB = srcB0 + (size_t)k0 * DD;
    f4 rv[4];
#pragma unroll
    for (int rr = 0; rr < 4; ++rr) rv[rr] = *(const f4*)(sB + (size_t)rr * DD);
#pragma unroll
    for (int q = 0; q < 4; ++q) {
      int n = 4 * bi + q;
      int sw = ((n >> 1) ^ (n >> 4)) & 7;
      Bs[n * 8 + (ka ^ sw)] = pack4bf(rv[0][q], rv[1][q], rv[2][q], rv[3][q]);
    }
    __syncthreads();
    s16x8 af2[4];
#pragma unroll
    for (int mt = 0; mt < 4; ++mt) {
      int row = wr + mt * 16 + lm;
      int sw = ((row >> 1) ^ (row >> 4)) & 7;
      int ua = (2 * grp) ^ sw;
      af2[mt] = mkfrag(As[row * 8 + ua], As[row * 8 + (ua ^ 1)]);
    }
#pragma unroll
    for (int nt = 0; nt < 4; ++nt) {
      int row = wc + nt * 16 + lm;
      int sw = ((row >> 1) ^ (row >> 4)) & 7;
      int ua = (2 * grp) ^ sw;
      s16x8 bf = mkfrag(Bs[row * 8 + ua], Bs[row * 8 + (ua ^ 1)]);
#pragma unroll
      for (int mt = 0; mt < 4; ++mt)
        acc[mt][nt] = mfma16b(af2[mt], bf, acc[mt][nt]);
    }
    __syncthreads();
  }
#pragma unroll
  for (int mt = 0; mt < 4; ++mt) {
    int rowb = m0 + wr + mt * 16 + grp * 4;
#pragma unroll
    for (int nt = 0; nt < 4; ++nt) {
      int col = n0 + wc + nt * 16 + lm;
#pragma unroll
      for (int q = 0; q < 4; ++q)
        Cb[(size_t)(rowb + q) * DD + col] = acc[mt][nt][q];
    }
  }
}

// ============ launch ============

extern "C" void kernel_launch(void* const* d_in, const int* in_sizes, int n_in,
                              void* d_out, int out_size, void* d_ws, size_t ws_size,
                              hipStream_t stream) {
  const float* Q = (const float*)d_in[0];   // "output": (B, Lq, D)
  const float* K = (const float*)d_in[1];   // "inputs": (B, Lk, D)
  float* ctx  = (float*)d_out;                           // (B, Lq, D)
  float* attn = (float*)d_out + (size_t)NB * LQ * DD;    // (B, Lq, Lk)

  const size_t nQh = (size_t)NB * LQ * DD;     // Qh fp16
  const size_t nKh = (size_t)NB * LK * DD;     // Kh fp16
  const size_t nKT = (size_t)NB * DD * LK;     // K^T fp16
  const size_t nPw = (size_t)NB * LQ * LK;     // scores fp16 -> P fp16 (in place)
  const size_t need = (nQh + nKh + nKT + nPw) * sizeof(_Float16);

  if (ws_size >= need) {
    _Float16* Qh = (_Float16*)d_ws;
    _Float16* Kh = Qh + nQh;
    _Float16* KT = Kh + nKh;
    _Float16* Pw = KT + nKT;

    (void)hipFuncSetAttribute((const void*)gemm8_f16,
                              hipFuncAttributeMaxDynamicSharedMemorySize, 131072);
    (void)hipFuncSetAttribute((const void*)gemm8_f32,
                              hipFuncAttributeMaxDynamicSharedMemorySize, 131072);

    conv_all<<<dim3(64, 16, NB), 256, 0, stream>>>(Q, K, Qh, Kh, KT);

    // S-125 = Qh * Kh^T - 125  (fp16 scores into Pw)
    gemm8_f16<<<dim3(LK / 256, LQ / 256, NB), 512, 131072, stream>>>(
        Qh, Kh, Pw, 1024, 1024, 1024, 1023, LK,
        (long)LQ * DD, (long)LK * DD, (long)LQ * LK);

    // softmax: Pw (fp16 shifted scores) -> attn fp32 + P fp16 (in place)
    softmax_f16<<<dim3(NB * LQ), 256, 0, stream>>>(Pw, attn);

    // ctx = Pw * KT^T = P * K
    gemm8_f32<<<dim3(DD / 256, LQ / 256, NB), 512, 131072, stream>>>(
        Pw, KT, ctx, 2048, 2048, 2048, 2047, DD,
        (long)LQ * LK, (long)DD * LK, (long)LQ * DD);
  } else {
    gemm1_scores<<<dim3(LK / 128, LQ / 128, NB), 256, 0, stream>>>(Q, K, attn);
    softmax_rows<<<dim3(NB * LQ), 256, 0, stream>>>(attn, nullptr);
    gemm2_ctx<<<dim3(DD / 128, LQ / 128, NB), 256, 0, stream>>>(attn, K, ctx);
  }
}

// Round 11
// 225.676 us; speedup vs baseline: 4.8894x; 1.0228x over previous
//
#include <hip/hip_runtime.h>

#define LQ 2048
#define LK 2048
#define DD 1024
#define NB 8
#define NSL 8192   // elements per (dbuf,half) region: 128 slots x 64 cols
#define SSHIFT 125.0f   // row-uniform score shift: centers high-p scores near 0 for fp16 storage

typedef __attribute__((ext_vector_type(4))) float f4;
typedef __attribute__((ext_vector_type(4))) float f32x4;
typedef __attribute__((ext_vector_type(8))) short s16x8;
typedef __attribute__((ext_vector_type(8))) _Float16 h16x8;
typedef __attribute__((ext_vector_type(4))) _Float16 h16x4;
typedef __attribute__((ext_vector_type(2))) unsigned long long u64x2_t;

__device__ __forceinline__ void gload_lds16(const _Float16* g, const _Float16* l) {
  __builtin_amdgcn_global_load_lds((const __attribute__((address_space(1))) void*)g,
                                   (__attribute__((address_space(3))) void*)l, 16, 0, 0);
}

// ============ fused conversions ============
// grid (64, 16, NB): x<32 -> K-conv (Kh + KT), x>=32 -> Q-conv (Qh)

__global__ __launch_bounds__(256) void conv_all(const float* __restrict__ Q,
                                                const float* __restrict__ K,
                                                _Float16* __restrict__ Qh,
                                                _Float16* __restrict__ Kh,
                                                _Float16* __restrict__ KT) {
  __shared__ _Float16 tile[64][66];
  const int b = blockIdx.z;
  const int t = threadIdx.x, tr = t >> 4, tc = t & 15;
  if (blockIdx.x >= 32) {
    const int r0 = (blockIdx.x - 32) * 64, d0 = blockIdx.y * 64;
    const float* Qb = Q + ((size_t)b * LQ + r0) * DD + d0;
    _Float16* Qo = Qh + ((size_t)b * LQ + r0) * DD + d0;
#pragma unroll
    for (int i = 0; i < 4; ++i) {
      int rr = tr + i * 16;
      f4 v = *(const f4*)(Qb + (size_t)rr * DD + tc * 4);
      h16x4 h;
#pragma unroll
      for (int j = 0; j < 4; ++j) h[j] = (_Float16)v[j];
      *(h16x4*)(Qo + (size_t)rr * DD + tc * 4) = h;
    }
  } else {
    const int k0 = blockIdx.x * 64, d0 = blockIdx.y * 64;
#pragma unroll
    for (int i = 0; i < 4; ++i) {
      int kk = tr + i * 16;
      f4 v = *(const f4*)(K + ((size_t)b * LK + k0 + kk) * DD + d0 + tc * 4);
      h16x4 h;
#pragma unroll
      for (int j = 0; j < 4; ++j) { h[j] = (_Float16)v[j]; tile[tc * 4 + j][kk] = h[j]; }
      *(h16x4*)(Kh + ((size_t)b * LK + k0 + kk) * DD + d0 + tc * 4) = h;
    }
    __syncthreads();
#pragma unroll
    for (int i = 0; i < 4; ++i) {
      int dd = tr + i * 16;
      h16x4 o;
#pragma unroll
      for (int j = 0; j < 4; ++j) o[j] = tile[dd][tc * 4 + j];
      *(h16x4*)(KT + ((size_t)b * DD + d0 + dd) * LK + k0 + tc * 4) = o;
    }
  }
}

// ============ 256x256 4-phase GEMM: C = A * B^T (round-8 verified best) ============
// 512 threads = 8 waves (2M x 4N); per-wave C = 128x64; BK=64, double-buffered
// halves; 4 phases of 32 MFMA per 2-K-tile iter; counted vmcnt; strictly-after
// staging ledger; XCD-chunked blockIdx swizzle (measured +8us vs none, R8 vs R10:
// keeps 256-row panel neighbors on one XCD's L2).

__device__ __forceinline__ void load_af(const _Float16* ASm, int p, int mh,
                                        int wm, int lm, int grp, h16x8 af[4][2]) {
#pragma unroll
  for (int mti = 0; mti < 4; ++mti) {
    int slot = wm * 64 + mti * 16 + lm;
    const _Float16* base = ASm + (p * 2 + mh) * NSL + slot * 64;
#pragma unroll
    for (int kb = 0; kb < 2; ++kb) {
      int uu = (kb * 4 + grp) ^ (slot & 7);
      af[mti][kb] = *(const h16x8*)(base + uu * 8);
    }
  }
}

__device__ __forceinline__ void load_bf(const _Float16* BSm, int p, int nh,
                                        int wn, int lm, int grp, h16x8 bf[2][2]) {
#pragma unroll
  for (int nti = 0; nti < 2; ++nti) {
    int slot = wn * 32 + nti * 16 + lm;
    const _Float16* base = BSm + (p * 2 + nh) * NSL + slot * 64;
#pragma unroll
    for (int kb = 0; kb < 2; ++kb) {
      int uu = (kb * 4 + grp) ^ (slot & 7);
      bf[nti][kb] = *(const h16x8*)(base + uu * 8);
    }
  }
}

__device__ __forceinline__ void mfma_pair(f32x4 acc[8][4], const h16x8 af[4][2],
                                          const h16x8 bf0[2][2], const h16x8 bf1[2][2],
                                          int mh) {
  __builtin_amdgcn_s_setprio(1);
#pragma unroll
  for (int nti = 0; nti < 2; ++nti)
#pragma unroll
    for (int mti = 0; mti < 4; ++mti)
#pragma unroll
      for (int kb = 0; kb < 2; ++kb)
        acc[mh * 4 + mti][nti] = __builtin_amdgcn_mfma_f32_16x16x32_f16(
            af[mti][kb], bf0[nti][kb], acc[mh * 4 + mti][nti], 0, 0, 0);
#pragma unroll
  for (int nti = 0; nti < 2; ++nti)
#pragma unroll
    for (int mti = 0; mti < 4; ++mti)
#pragma unroll
      for (int kb = 0; kb < 2; ++kb)
        acc[mh * 4 + mti][2 + nti] = __builtin_amdgcn_mfma_f32_16x16x32_f16(
            af[mti][kb], bf1[nti][kb], acc[mh * 4 + mti][2 + nti], 0, 0, 0);
  __builtin_amdgcn_s_setprio(0);
}

__device__ __forceinline__ void pre_mfma() { __builtin_amdgcn_sched_barrier(0); }
__device__ __forceinline__ void phase_end() { __builtin_amdgcn_s_barrier(); }
__device__ __forceinline__ void phase_end_v6() {
  asm volatile("s_waitcnt vmcnt(6)" ::: "memory");
  __builtin_amdgcn_s_barrier();
}
__device__ __forceinline__ void phase_end_v4() {
  asm volatile("s_waitcnt vmcnt(4)" ::: "memory");
  __builtin_amdgcn_s_barrier();
}

template <typename OutT>
__device__ __forceinline__ void gemm8_body(
    const _Float16* __restrict__ A, const _Float16* __restrict__ B, OutT* __restrict__ C,
    int Klen, int lda, int ldb, int kmask, int ldc, long sA, long sB, long sC,
    float cshift, _Float16* smem) {
  _Float16* ASm = smem;
  _Float16* BSm = smem + 4 * NSL;

  const int nwgx = gridDim.x, nwgy = gridDim.y;
  const int nwg = nwgx * nwgy * gridDim.z;
  const int lin = blockIdx.x + nwgx * (blockIdx.y + nwgy * blockIdx.z);
  const int swzid = (lin & 7) * (nwg >> 3) + (lin >> 3);   // XCD-chunked (nwg%8==0)
  const int bx = swzid % nwgx;
  const int rest = swzid / nwgx;
  const int by = rest % nwgy, bz = rest / nwgy;

  const _Float16* Ab = A + (size_t)bz * sA;
  const _Float16* Bb = B + (size_t)bz * sB;
  OutT* Cb = C + (size_t)bz * sC;
  const int m0 = by * 256, n0 = bx * 256;

  const int tid = threadIdx.x, lane = tid & 63, w = tid >> 6;
  const int wm = w >> 2, wn = w & 3;
  const int lm = lane & 15, grp = lane >> 4;

  const _Float16* pAj[2];
  const _Float16* pBj[2];
#pragma unroll
  for (int j = 0; j < 2; ++j) {
    int s = (j * 8 + w) * 8 + (lane >> 3);
    int colp = ((lane & 7) ^ (s & 7)) * 8;
    int rA = (s & 63) | ((s >> 6) << 7);
    int rB = (s & 31) | ((s >> 5) << 6);
    pAj[j] = Ab + (size_t)(m0 + rA) * lda + colp;
    pBj[j] = Bb + (size_t)(n0 + rB) * ldb + colp;
  }
  const size_t hA = (size_t)64 * lda;
  const size_t hB = (size_t)32 * ldb;

#define STAGE_A(p, h, kk) do { \
    gload_lds16(pAj[0] + ((h) ? hA : 0) + (kk), ASm + ((p) * 2 + (h)) * NSL + w * 512); \
    gload_lds16(pAj[1] + ((h) ? hA : 0) + (kk), ASm + ((p) * 2 + (h)) * NSL + 4096 + w * 512); \
  } while (0)
#define STAGE_B(p, h, kk) do { \
    gload_lds16(pBj[0] + ((h) ? hB : 0) + (kk), BSm + ((p) * 2 + (h)) * NSL + w * 512); \
    gload_lds16(pBj[1] + ((h) ? hB : 0) + (kk), BSm + ((p) * 2 + (h)) * NSL + 4096 + w * 512); \
  } while (0)

  f32x4 acc[8][4] = {};
  const int NT = Klen / 64;

  // prologue: tile0 {A0,B1,A1,B0} (8 loads) + tile1 {A0,B1} (4 loads); vmcnt(4)
  STAGE_A(0, 0, 0);
  STAGE_B(0, 1, 0);
  STAGE_A(0, 1, 0);
  STAGE_B(0, 0, 0);
  STAGE_A(1, 0, 64);
  STAGE_B(1, 1, 64 & kmask);
  asm volatile("s_waitcnt vmcnt(4)" ::: "memory");
  __builtin_amdgcn_s_barrier();

  h16x8 af[4][2], bf0[2][2], bf1[2][2];

  for (int it = 0; it < NT / 2; ++it) {
    const int t = 2 * it;
    const int kt1 = (t + 1) * 64;
    const int kt2 = ((t + 2 < NT) ? (t + 2) : (NT - 1)) * 64;
    const int kt3 = ((t + 3 < NT) ? (t + 3) : (NT - 1)) * 64;
    const int kt1b = kt1 & kmask, kt2b = kt2 & kmask, kt3b = kt3 & kmask;

    // P1: tile t (buffer 0), quads (0,0),(0,1)
    load_af(ASm, 0, 0, wm, lm, grp, af);
    load_bf(BSm, 0, 0, wn, lm, grp, bf0);
    load_bf(BSm, 0, 1, wn, lm, grp, bf1);
    STAGE_B(1, 0, kt1b);     // B0q <- t+1 (last read: prev P3)
    STAGE_A(1, 1, kt1);      // A1q <- t+1 (last read: prev P4)
    pre_mfma(); mfma_pair(acc, af, bf0, bf1, 0); phase_end();

    // P2: quads (1,0),(1,1) — bf0/bf1 reused from registers
    load_af(ASm, 0, 1, wm, lm, grp, af);
    STAGE_A(0, 0, kt2);      // A0p <- t+2 (read P1)
    STAGE_B(0, 1, kt2b);     // B1p <- t+2 (read P1)
    STAGE_B(0, 0, kt2b);     // B0p <- t+2 (read P1)
    pre_mfma(); mfma_pair(acc, af, bf0, bf1, 1);
    phase_end_v6();          // tile t+1 fully landed

    // P3: tile t+1 (buffer 1), quads (0,0),(0,1)
    load_af(ASm, 1, 0, wm, lm, grp, af);
    load_bf(BSm, 1, 0, wn, lm, grp, bf0);
    load_bf(BSm, 1, 1, wn, lm, grp, bf1);
    STAGE_A(0, 1, kt2);      // A1p <- t+2 (read P2)
    pre_mfma(); mfma_pair(acc, af, bf0, bf1, 0); phase_end();

    // P4: quads (1,0),(1,1)
    load_af(ASm, 1, 1, wm, lm, grp, af);
    STAGE_A(1, 0, kt3);      // A0q <- t+3 (read P3)
    STAGE_B(1, 1, kt3b);     // B1q <- t+3 (read P3)
    pre_mfma(); mfma_pair(acc, af, bf0, bf1, 1);
    phase_end_v4();          // tile t+2 fully landed
  }

#pragma unroll
  for (int mh = 0; mh < 2; ++mh)
#pragma unroll
    for (int mti = 0; mti < 4; ++mti) {
      int row0 = m0 + wm * 128 + mh * 64 + mti * 16 + grp * 4;
#pragma unroll
      for (int nh = 0; nh < 2; ++nh)
#pragma unroll
        for (int nti = 0; nti < 2; ++nti) {
          int col = n0 + wn * 64 + nh * 32 + nti * 16 + lm;
#pragma unroll
          for (int qq = 0; qq < 4; ++qq)
            Cb[(size_t)(row0 + qq) * ldc + col] =
                (OutT)(acc[mh * 4 + mti][nh * 2 + nti][qq] + cshift);
        }
    }
#undef STAGE_A
#undef STAGE_B
}

__global__ __launch_bounds__(512, 2) void gemm8_f32(
    const _Float16* __restrict__ A, const _Float16* __restrict__ B, float* __restrict__ C,
    int Klen, int lda, int ldb, int kmask, int ldc, long sA, long sB, long sC) {
  extern __shared__ _Float16 smem[];
  gemm8_body<float>(A, B, C, Klen, lda, ldb, kmask, ldc, sA, sB, sC, 0.0f, smem);
}

__global__ __launch_bounds__(512, 2) void gemm8_f16(
    const _Float16* __restrict__ A, const _Float16* __restrict__ B, _Float16* __restrict__ C,
    int Klen, int lda, int ldb, int kmask, int ldc, long sA, long sB, long sC) {
  extern __shared__ _Float16 smem[];
  gemm8_body<_Float16>(A, B, C, Klen, lda, ldb, kmask, ldc, sA, sB, sC, -SSHIFT, smem);
}

// ============ softmax (fp16 scores in-place -> P fp16; attn fp32 out) ============

__global__ __launch_bounds__(256) void softmax_f16(_Float16* __restrict__ SP,
                                                   float* __restrict__ A) {
  __shared__ float red[4];
  const int row = blockIdx.x;
  _Float16* pr = SP + (size_t)row * LK;
  const int t = threadIdx.x, lane = t & 63, w = t >> 6;
  h16x8 v = *(const h16x8*)(pr + t * 8);
  float x[8];
#pragma unroll
  for (int i = 0; i < 8; ++i) x[i] = (float)v[i];

  float m = x[0];
#pragma unroll
  for (int i = 1; i < 8; ++i) m = fmaxf(m, x[i]);
#pragma unroll
  for (int off = 32; off > 0; off >>= 1) m = fmaxf(m, __shfl_xor(m, off));
  if (lane == 0) red[w] = m;
  __syncthreads();
  m = fmaxf(fmaxf(red[0], red[1]), fmaxf(red[2], red[3]));
  __syncthreads();

  float e[8];
  float s = 0.f;
#pragma unroll
  for (int i = 0; i < 8; ++i) { e[i] = __expf(x[i] - m); s += e[i]; }
#pragma unroll
  for (int off = 32; off > 0; off >>= 1) s += __shfl_xor(s, off);
  if (lane == 0) red[w] = s;
  __syncthreads();
  s = red[0] + red[1] + red[2] + red[3];
  const float inv = 1.0f / s;

  f4 a0, a1;
  h16x8 o;
#pragma unroll
  for (int i = 0; i < 8; ++i) {
    float y = e[i] * inv;
    if (i < 4) a0[i] = y; else a1[i - 4] = y;
    o[i] = (_Float16)y;
  }
  float* ar = A + (size_t)row * LK + t * 8;
  *(f4*)ar = a0;
  *(f4*)(ar + 4) = a1;
  *(h16x8*)(pr + t * 8) = o;
}

// ============ fp32 softmax (fallback path) ============

__global__ __launch_bounds__(256) void softmax_rows(float* __restrict__ S,
                                                    _Float16* __restrict__ P) {
  __shared__ float red[4];
  const int row = blockIdx.x;
  float* p = S + (size_t)row * LK;
  const int t = threadIdx.x;
  const int lane = t & 63, w = t >> 6;
  f4* p4 = (f4*)p;
  f4 v0 = p4[t], v1 = p4[t + 256];

  float m = fmaxf(fmaxf(fmaxf(v0[0], v0[1]), fmaxf(v0[2], v0[3])),
                  fmaxf(fmaxf(v1[0], v1[1]), fmaxf(v1[2], v1[3])));
#pragma unroll
  for (int off = 32; off > 0; off >>= 1) m = fmaxf(m, __shfl_xor(m, off));
  if (lane == 0) red[w] = m;
  __syncthreads();
  m = fmaxf(fmaxf(red[0], red[1]), fmaxf(red[2], red[3]));
  __syncthreads();

  f4 e0, e1;
  float s = 0.f;
#pragma unroll
  for (int i = 0; i < 4; ++i) { e0[i] = __expf(v0[i] - m); s += e0[i]; }
#pragma unroll
  for (int i = 0; i < 4; ++i) { e1[i] = __expf(v1[i] - m); s += e1[i]; }
#pragma unroll
  for (int off = 32; off > 0; off >>= 1) s += __shfl_xor(s, off);
  if (lane == 0) red[w] = s;
  __syncthreads();
  s = red[0] + red[1] + red[2] + red[3];
  float inv = 1.0f / s;
  e0 *= inv; e1 *= inv;
  p4[t] = e0; p4[t + 256] = e1;
  if (P) {
    h16x4 a, bb;
#pragma unroll
    for (int i = 0; i < 4; ++i) { a[i] = (_Float16)e0[i]; bb[i] = (_Float16)e1[i]; }
    _Float16* pr = P + (size_t)row * LK;
    *(h16x4*)(pr + t * 4) = a;
    *(h16x4*)(pr + 1024 + t * 4) = bb;
  }
}

// ============ fallback path (split-bf16, no workspace) ============

__device__ __forceinline__ unsigned int f2bf_bits(float x) {
  unsigned int u = __float_as_uint(x);
  return (u + 0x7fffu + ((u >> 16) & 1u)) >> 16;
}
__device__ __forceinline__ float bf2f(unsigned int h) { return __uint_as_float(h << 16); }
__device__ __forceinline__ void hilo4(const f4 v, unsigned long long& ph, unsigned long long& pl) {
  unsigned int h[4], l[4];
#pragma unroll
  for (int i = 0; i < 4; ++i) {
    h[i] = f2bf_bits(v[i]);
    float rr = v[i] - bf2f(h[i]);
    l[i] = f2bf_bits(rr);
  }
  ph = (unsigned long long)h[0] | ((unsigned long long)h[1] << 16) |
       ((unsigned long long)h[2] << 32) | ((unsigned long long)h[3] << 48);
  pl = (unsigned long long)l[0] | ((unsigned long long)l[1] << 16) |
       ((unsigned long long)l[2] << 32) | ((unsigned long long)l[3] << 48);
}
__device__ __forceinline__ unsigned long long pack4bf(float a, float b, float c, float d) {
  return (unsigned long long)f2bf_bits(a) | ((unsigned long long)f2bf_bits(b) << 16) |
         ((unsigned long long)f2bf_bits(c) << 32) | ((unsigned long long)f2bf_bits(d) << 48);
}
__device__ __forceinline__ s16x8 mkfrag(unsigned long long u0, unsigned long long u1) {
  u64x2_t t; t[0] = u0; t[1] = u1;
  return __builtin_bit_cast(s16x8, t);
}
__device__ __forceinline__ f32x4 mfma16b(s16x8 a, s16x8 b, f32x4 c) {
  return __builtin_amdgcn_mfma_f32_16x16x32_bf16(a, b, c, 0, 0, 0);
}

__global__ __launch_bounds__(256) void gemm1_scores(
    const float* __restrict__ Q, const float* __restrict__ K, float* __restrict__ S) {
  __shared__ unsigned long long Ah[128 * 8], Al[128 * 8], Bh[128 * 8], Bl[128 * 8];
  const int b = blockIdx.z;
  const float* Qb = Q + (size_t)b * LQ * DD;
  const float* Kb = K + (size_t)b * LK * DD;
  float* Sb = S + (size_t)b * LQ * LK;
  const int m0 = blockIdx.y * 128, n0 = blockIdx.x * 128;
  const int t = threadIdx.x;
  const int lane = t & 63, w = t >> 6;
  const int wr = (w >> 1) * 64, wc = (w & 1) * 64;
  const int lm = lane & 15, grp = lane >> 4;
  f32x4 acc[4][4] = {};
  const int r = t >> 1, hf = t & 1;
  const int sw_st = ((r >> 1) ^ (r >> 4)) & 7;
  const f4* srcA = (const f4*)(Qb + (size_t)(m0 + r) * DD) + hf * 4;
  const f4* srcB = (const f4*)(Kb + (size_t)(n0 + r) * DD) + hf * 4;
  for (int k0 = 0; k0 < DD; k0 += 32) {
#pragma unroll
    for (int u = 0; u < 4; ++u) {
      f4 v = srcA[u];
      unsigned long long ph, pl;
      hilo4(v, ph, pl);
      int idx = r * 8 + ((hf * 4 + u) ^ sw_st);
      Ah[idx] = ph; Al[idx] = pl;
    }
#pragma unroll
    for (int u = 0; u < 4; ++u) {
      f4 v = srcB[u];
      unsigned long long ph, pl;
      hilo4(v, ph, pl);
      int idx = r * 8 + ((hf * 4 + u) ^ sw_st);
      Bh[idx] = ph; Bl[idx] = pl;
    }
    srcA += 8; srcB += 8;
    __syncthreads();
    s16x8 afh[4], afl[4];
#pragma unroll
    for (int mt = 0; mt < 4; ++mt) {
      int row = wr + mt * 16 + lm;
      int sw = ((row >> 1) ^ (row >> 4)) & 7;
      int ua = (2 * grp) ^ sw;
      int base = row * 8;
      afh[mt] = mkfrag(Ah[base + ua], Ah[base + (ua ^ 1)]);
      afl[mt] = mkfrag(Al[base + ua], Al[base + (ua ^ 1)]);
    }
#pragma unroll
    for (int nt = 0; nt < 4; ++nt) {
      int row = wc + nt * 16 + lm;
      int sw = ((row >> 1) ^ (row >> 4)) & 7;
      int ua = (2 * grp) ^ sw;
      int base = row * 8;
      s16x8 bfh = mkfrag(Bh[base + ua], Bh[base + (ua ^ 1)]);
      s16x8 bfl = mkfrag(Bl[base + ua], Bl[base + (ua ^ 1)]);
#pragma unroll
      for (int mt = 0; mt < 4; ++mt) {
        acc[mt][nt] = mfma16b(afh[mt], bfh, acc[mt][nt]);
        acc[mt][nt] = mfma16b(afh[mt], bfl, acc[mt][nt]);
        acc[mt][nt] = mfma16b(afl[mt], bfh, acc[mt][nt]);
      }
    }
    __syncthreads();
  }
#pragma unroll
  for (int mt = 0; mt < 4; ++mt) {
    int rowb = m0 + wr + mt * 16 + grp * 4;
#pragma unroll
    for (int nt = 0; nt < 4; ++nt) {
      int col = n0 + wc + nt * 16 + lm;
#pragma unroll
      for (int q = 0; q < 4; ++q)
        Sb[(size_t)(rowb + q) * LK + col] = acc[mt][nt][q];
    }
  }
}

__global__ __launch_bounds__(256) void gemm2_ctx(
    const float* __restrict__ P, const float* __restrict__ K, float* __restrict__ C) {
  __shared__ unsigned long long As[128 * 8], Bs[128 * 8];
  const int b = blockIdx.z;
  const float* Pb = P + (size_t)b * LQ * LK;
  const float* Kb = K + (size_t)b * LK * DD;
  float* Cb = C + (size_t)b * LQ * DD;
  const int m0 = blockIdx.y * 128, n0 = blockIdx.x * 128;
  const int t = threadIdx.x, lane = t & 63, w = t >> 6;
  const int wr = (w >> 1) * 64, wc = (w & 1) * 64;
  const int lm = lane & 15, grp = lane >> 4;
  f32x4 acc[4][4] = {};
  const int r = t >> 1, hf = t & 1;
  const int sw_a = ((r >> 1) ^ (r >> 4)) & 7;
  const f4* srcA = (const f4*)(Pb + (size_t)(m0 + r) * LK) + hf * 4;
  const int ka = t >> 5, bi = t & 31;
  const float* srcB0 = Kb + (size_t)(4 * ka) * DD + n0 + 4 * bi;
  for (int k0 = 0; k0 < LK; k0 += 32) {
#pragma unroll
    for (int u = 0; u < 4; ++u) {
      f4 v = srcA[u];
      As[r * 8 + ((hf * 4 + u) ^ sw_a)] = pack4bf(v[0], v[1], v[2], v[3]);
    }
    srcA += 8;
    const float* sB = srcB0 + (size_t)k0 * DD;
    f4 rv[4];
#pragma unroll
    for (int rr = 0; rr < 4; ++rr) rv[rr] = *(const f4*)(sB + (size_t)rr * DD);
#pragma unroll
    for (int q = 0; q < 4; ++q) {
      int n = 4 * bi + q;
      int sw = ((n >> 1) ^ (n >> 4)) & 7;
      Bs[n * 8 + (ka ^ sw)] = pack4bf(rv[0][q], rv[1][q], rv[2][q], rv[3][q]);
    }
    __syncthreads();
    s16x8 af2[4];
#pragma unroll
    for (int mt = 0; mt < 4; ++mt) {
      int row = wr + mt * 16 + lm;
      int sw = ((row >> 1) ^ (row >> 4)) & 7;
      int ua = (2 * grp) ^ sw;
      af2[mt] = mkfrag(As[row * 8 + ua], As[row * 8 + (ua ^ 1)]);
    }
#pragma unroll
    for (int nt = 0; nt < 4; ++nt) {
      int row = wc + nt * 16 + lm;
      int sw = ((row >> 1) ^ (row >> 4)) & 7;
      int ua = (2 * grp) ^ sw;
      s16x8 bf = mkfrag(Bs[row * 8 + ua], Bs[row * 8 + (ua ^ 1)]);
#pragma unroll
      for (int mt = 0; mt < 4; ++mt)
        acc[mt][nt] = mfma16b(af2[mt], bf, acc[mt][nt]);
    }
    __syncthreads();
  }
#pragma unroll
  for (int mt = 0; mt < 4; ++mt) {
    int rowb = m0 + wr + mt * 16 + grp * 4;
#pragma unroll
    for (int nt = 0; nt < 4; ++nt) {
      int col = n0 + wc + nt * 16 + lm;
#pragma unroll
      for (int q = 0; q < 4; ++q)
        Cb[(size_t)(rowb + q) * DD + col] = acc[mt][nt][q];
    }
  }
}

// ============ launch ============

extern "C" void kernel_launch(void* const* d_in, const int* in_sizes, int n_in,
                              void* d_out, int out_size, void* d_ws, size_t ws_size,
                              hipStream_t stream) {
  const float* Q = (const float*)d_in[0];   // "output": (B, Lq, D)
  const float* K = (const float*)d_in[1];   // "inputs": (B, Lk, D)
  float* ctx  = (float*)d_out;                           // (B, Lq, D)
  float* attn = (float*)d_out + (size_t)NB * LQ * DD;    // (B, Lq, Lk)

  const size_t nQh = (size_t)NB * LQ * DD;     // Qh fp16
  const size_t nKh = (size_t)NB * LK * DD;     // Kh fp16
  const size_t nKT = (size_t)NB * DD * LK;     // K^T fp16
  const size_t nPw = (size_t)NB * LQ * LK;     // scores fp16 -> P fp16 (in place)
  const size_t need = (nQh + nKh + nKT + nPw) * sizeof(_Float16);

  if (ws_size >= need) {
    _Float16* Qh = (_Float16*)d_ws;
    _Float16* Kh = Qh + nQh;
    _Float16* KT = Kh + nKh;
    _Float16* Pw = KT + nKT;

    (void)hipFuncSetAttribute((const void*)gemm8_f16,
                              hipFuncAttributeMaxDynamicSharedMemorySize, 131072);
    (void)hipFuncSetAttribute((const void*)gemm8_f32,
                              hipFuncAttributeMaxDynamicSharedMemorySize, 131072);

    conv_all<<<dim3(64, 16, NB), 256, 0, stream>>>(Q, K, Qh, Kh, KT);

    // S-125 = Qh * Kh^T - 125  (fp16 scores into Pw)
    gemm8_f16<<<dim3(LK / 256, LQ / 256, NB), 512, 131072, stream>>>(
        Qh, Kh, Pw, 1024, 1024, 1024, 1023, LK,
        (long)LQ * DD, (long)LK * DD, (long)LQ * LK);

    // softmax: Pw (fp16 shifted scores) -> attn fp32 + P fp16 (in place)
    softmax_f16<<<dim3(NB * LQ), 256, 0, stream>>>(Pw, attn);

    // ctx = Pw * KT^T = P * K
    gemm8_f32<<<dim3(DD / 256, LQ / 256, NB), 512, 131072, stream>>>(
        Pw, KT, ctx, 2048, 2048, 2048, 2047, DD,
        (long)LQ * LK, (long)DD * LK, (long)LQ * DD);
  } else {
    gemm1_scores<<<dim3(LK / 128, LQ / 128, NB), 256, 0, stream>>>(Q, K, attn);
    softmax_rows<<<dim3(NB * LQ), 256, 0, stream>>>(attn, nullptr);
    gemm2_ctx<<<dim3(DD / 128, LQ / 128, NB), 256, 0, stream>>>(attn, K, ctx);
  }
}